// Round 14
// baseline (231.434 us; speedup 1.0000x reference)
//
#include <hip/hip_runtime.h>
#include <hip/hip_bf16.h>
#include <math.h>

#define D_  1024
#define L_  1024
#define B_  4
#define H_  16
#define HD_ 64

typedef __attribute__((ext_vector_type(4))) short short4_t;
typedef __attribute__((ext_vector_type(8))) short short8_t;
typedef __attribute__((ext_vector_type(4))) float f4;
typedef unsigned short u16;

__device__ __forceinline__ f4 MF(short8_t a, short8_t b, f4 c) {
  return __builtin_amdgcn_mfma_f32_16x16x32_bf16(a, b, c, 0, 0, 0);
}
__device__ __forceinline__ unsigned fbits(float x) { return __builtin_bit_cast(unsigned, x); }
__device__ __forceinline__ float bf2f(unsigned short u) {
  return __builtin_bit_cast(float, (unsigned)u << 16);
}
__device__ __forceinline__ unsigned pack2hi(float x, float y) {
  return (fbits(x) >> 16) | (fbits(y) & 0xFFFF0000u);
}
__device__ __forceinline__ float bfres(float x) {  // x - trunc_bf16(x)
  return x - __builtin_bit_cast(float, fbits(x) & 0xFFFF0000u);
}
__device__ __forceinline__ float ftanh(float x) {  // |x| small here; err < 2e-6
  float t = __expf(2.f * x);
  return (t - 1.f) / (t + 1.f);
}
__device__ __forceinline__ void gload16(const void* g, void* l) {
  __builtin_amdgcn_global_load_lds(
      (const __attribute__((address_space(1))) unsigned*)g,
      (__attribute__((address_space(3))) unsigned*)l, 16, 0, 0);
}
// ONE ds_read_b128 per MFMA fragment (attn): planes store the k-axis
// pre-permuted within 32-blocks, staging XORs 16B chunks (scol), so chunk
// ci=(kc*4+g)^(row&7) holds the full fragment.
__device__ __forceinline__ short8_t ldsfragP(const char* base, int row, int ci) {
  return *(const short8_t*)(base + row * 128 + ((ci ^ (row & 7)) << 4));
}
// permute a 4-aligned column index within its 32-block
__device__ __forceinline__ int perm32(int c) {
  return (c & ~31) | (((c >> 2) & 3) << 3) | (((c >> 4) & 1) << 2);
}

// ---------------------------------------------------------------------------
// Kernel 1 (fused prep): wgen (blocks 0..3071), hscvt (3072..7167),
// ecvt (7168..7295), bgen (7296..7307).
// ---------------------------------------------------------------------------
__global__ __launch_bounds__(256) void prep_kernel(
    const float* __restrict__ tw, const float* __restrict__ wlw,
    const float* __restrict__ scw, const float* __restrict__ shw,
    const float* __restrict__ hs,
    const float* __restrict__ tb, const float* __restrict__ wlb,
    const float* __restrict__ scb, const float* __restrict__ shb,
    const float* __restrict__ emb,
    u16* __restrict__ whi, u16* __restrict__ wlo,
    u16* __restrict__ hhi, u16* __restrict__ hlo,
    u16* __restrict__ embh, float* __restrict__ b_s) {
  const int blk = blockIdx.x;
  const int tid = threadIdx.x;
  if (blk < 3072) {
    // ---- wgen ----
    size_t i4 = (size_t)blk * 256 + tid;
    size_t e = i4 * 4;
    int p = (int)(e >> 20);
    size_t rem = e & 0xFFFFFu;
    float a0 = wlw[p * 2 + 0], a1 = wlw[p * 2 + 1];
    float4 t0 = *(const float4*)&tw[((size_t)(p * 2 + 0) << 20) + rem];
    float4 t1 = *(const float4*)&tw[((size_t)(p * 2 + 1) << 20) + rem];
    float4 s4 = *(const float4*)&scw[e];
    float4 h4 = *(const float4*)&shw[e];
    float4 o;
    o.x = ftanh(a0 * t0.x + a1 * t1.x) * s4.x + h4.x;
    o.y = ftanh(a0 * t0.y + a1 * t1.y) * s4.y + h4.y;
    o.z = ftanh(a0 * t0.z + a1 * t1.z) * s4.z + h4.z;
    o.w = ftanh(a0 * t0.w + a1 * t1.w) * s4.w + h4.w;
    const size_t off = (e & ~(size_t)31) + perm32((int)(e & 31));
    uint2 hi; hi.x = pack2hi(o.x, o.y); hi.y = pack2hi(o.z, o.w);
    *(uint2*)&whi[off] = hi;
    uint2 lo; lo.x = pack2hi(bfres(o.x), bfres(o.y)); lo.y = pack2hi(bfres(o.z), bfres(o.w));
    *(uint2*)&wlo[off] = lo;
  } else if (blk < 7168) {
    // ---- hscvt ----
    size_t i4 = (size_t)(blk - 3072) * 256 + tid;
    size_t e = i4 * 4;
    float4 v = *(const float4*)&hs[e];
    const size_t off = (e & ~(size_t)31) + perm32((int)(e & 31));
    uint2 hi; hi.x = pack2hi(v.x, v.y); hi.y = pack2hi(v.z, v.w);
    *(uint2*)&hhi[off] = hi;
    uint2 lo; lo.x = pack2hi(bfres(v.x), bfres(v.y)); lo.y = pack2hi(bfres(v.z), bfres(v.w));
    *(uint2*)&hlo[off] = lo;
  } else if (blk < 7296) {
    // ---- ecvt ----
    int i4 = (blk - 7168) * 256 + tid;
    if (i4 >= 32752) return;   // 2047*64/4
    int e = i4 * 4;
    float4 v = *(const float4*)&emb[e];
    uint2 h2; h2.x = pack2hi(v.x, v.y); h2.y = pack2hi(v.z, v.w);
    int pe = (e & ~31) | perm32(e & 31);
    *(uint2*)&embh[pe] = h2;
  } else {
    // ---- bgen ----
    int i = (blk - 7296) * 256 + tid;   // 0..3071
    int p = i >> 10;
    int o = i & 1023;
    float v = ftanh(wlb[p * 2 + 0] * tb[(p * 2 + 0) * D_ + o] +
                    wlb[p * 2 + 1] * tb[(p * 2 + 1) * D_ + o]);
    b_s[i] = v * scb[i] + shb[i];
  }
}

// ---------------------------------------------------------------------------
// Kernel 3: QKV projection, bf16x3 MFMA, double-buffered staging with a
// single barrier per K-tile. LDS dest wave-uniform (rule m104). Slot map:
// A -> SB[.][0/1], B -> SB[.][2/3].  64 KB LDS -> 2 blocks/CU.
// ---------------------------------------------------------------------------
__global__ __launch_bounds__(256, 2) void proj_mfma_kernel(
    const u16* __restrict__ Ahp, const u16* __restrict__ Alp,
    const u16* __restrict__ Bhp, const u16* __restrict__ Blp,
    const float* __restrict__ bias,
    u16* __restrict__ Qhi, u16* __restrict__ Qlo,
    u16* __restrict__ Khi, u16* __restrict__ Klo,
    u16* __restrict__ Vthi, u16* __restrict__ Vtlo) {
  __shared__ u16 SB[2][4][128][32];   // [buf][Ah,Al,Bh,Bl][row][col] = 64 KB
  const int tid  = threadIdx.x;
  const int lane = tid & 63;
  const int wv   = tid >> 6;
  const int wm   = wv >> 1, wn = wv & 1;
  const int l15  = lane & 15, g = lane >> 4;

  const int bid = (blockIdx.x & 7) * 96 + (blockIdx.x >> 3);  // XCD swizzle
  const int mt = bid & 31, nt = bid >> 5;
  const int m0 = mt * 128, n0 = nt * 128;

  f4 acc[4][4];
#pragma unroll
  for (int i = 0; i < 4; ++i)
#pragma unroll
    for (int j = 0; j < 4; ++j) acc[i][j] = f4{0.f, 0.f, 0.f, 0.f};

  const int srow = lane >> 2;            // 0..15 within a 16-row group
  const int sck  = (lane & 3) * 8;       // u16 offset 0,8,16,24

  // ---- per-wave staging descriptors (8 gload16/thread per K-tile) ----
  const u16* sbase[8];
  u16* sdst[8];
#pragma unroll
  for (int s = 0; s < 8; ++s) {
    const int q = wv * 8 + s;          // 0..31
    const int mat   = q >> 4;          // 0 = B, 1 = A
    const int plane = (q >> 3) & 1;    // 0 = hi, 1 = lo
    const int rowg  = q & 7;
    const u16* base = mat ? (plane ? Alp : Ahp) : (plane ? Blp : Bhp);
    const int  rb   = mat ? m0 : n0;
    sbase[s] = base + (size_t)(rb + rowg * 16 + srow) * 1024 + sck;
    sdst[s]  = &SB[0][(mat ^ 1) * 2 + plane][rowg * 16][0];   // A->0/1, B->2/3
  }

  // prologue: stage K-tile 0 into buf 0
#pragma unroll
  for (int s = 0; s < 8; ++s) gload16(sbase[s], sdst[s]);

#pragma unroll 2
  for (int kt = 0; kt < 32; ++kt) {
    const int cur = kt & 1;
    __syncthreads();   // drains staging(cur); prev-iter frag reads done

    if (kt < 31) {
      const int k1 = (kt + 1) * 32;
      const int bo = (cur ^ 1) * 16384;   // u16 offset of other buffer
#pragma unroll
      for (int s = 0; s < 8; ++s) gload16(sbase[s] + k1, sdst[s] + bo);
    }

    const u16 (*SBc)[128][32] = SB[cur];
    short8_t ah[4], al[4], bh[4], bl[4];
#pragma unroll
    for (int i = 0; i < 4; ++i) {
      ah[i] = *(const short8_t*)&SBc[0][wm * 64 + i * 16 + l15][g * 8];
      al[i] = *(const short8_t*)&SBc[1][wm * 64 + i * 16 + l15][g * 8];
      bh[i] = *(const short8_t*)&SBc[2][wn * 64 + i * 16 + l15][g * 8];
      bl[i] = *(const short8_t*)&SBc[3][wn * 64 + i * 16 + l15][g * 8];
    }
    __builtin_amdgcn_s_setprio(1);
#pragma unroll
    for (int mi = 0; mi < 4; ++mi)
#pragma unroll
      for (int ni = 0; ni < 4; ++ni) {
        acc[mi][ni] = MF(ah[mi], bh[ni], acc[mi][ni]);
        acc[mi][ni] = MF(ah[mi], bl[ni], acc[mi][ni]);
        acc[mi][ni] = MF(al[mi], bh[ni], acc[mi][ni]);
      }
    __builtin_amdgcn_s_setprio(0);
  }

  // ---- epilogue: per-mi LDS transpose -> coalesced uint2 plane stores ----
  const int p = n0 >> 10;
  const int h0 = (n0 >> 6) & 15;
  const int nbase = n0 + wn * 64;
  float bnv[4];
#pragma unroll
  for (int ni = 0; ni < 4; ++ni) bnv[ni] = bias[nbase + ni * 16 + l15];
  float* T = (float*)&SB[0][0][0][0];   // 32 x 132 f32

#pragma unroll
  for (int mi = 0; mi < 4; ++mi) {
    __syncthreads();
#pragma unroll
    for (int ni = 0; ni < 4; ++ni)
#pragma unroll
      for (int r = 0; r < 4; ++r)
        T[(wm * 16 + 4 * g + r) * 132 + wn * 64 + ni * 16 + l15] =
            acc[mi][ni][r] + bnv[ni];
    __syncthreads();

    if (p < 2) {
      u16* PH = p ? Khi : Qhi;
      u16* PL = p ? Klo : Qlo;
      const int lr = tid >> 3;
      const int m = m0 + (lr >> 4) * 64 + mi * 16 + (lr & 15);
      const int bb = m >> 10, l = m & 1023;
#pragma unroll
      for (int c = 0; c < 4; ++c) {
        const int col = 4 * (tid & 7) + 32 * c;
        const int pc = perm32(col & 63) | (col & 64);
        const int hd = pc & 63, hl = col >> 6;
        float4 v = *(const float4*)&T[lr * 132 + col];
        uint2 hi; hi.x = pack2hi(v.x, v.y); hi.y = pack2hi(v.z, v.w);
        uint2 lo; lo.x = pack2hi(bfres(v.x), bfres(v.y)); lo.y = pack2hi(bfres(v.z), bfres(v.w));
        const size_t ad = ((size_t)(bb * 16 + h0 + hl) << 16) + (size_t)l * 64 + hd;
        *(uint2*)&PH[ad] = hi;
        *(uint2*)&PL[ad] = lo;
      }
    } else {
      const int col = (tid >> 3) & 31;
#pragma unroll
      for (int c = 0; c < 4; ++c) {
        const int cc = col + 32 * c;
        const int hd = cc & 63, hl = cc >> 6;
        const int mq = tid & 7;
        const int lr0 = 4 * mq;
        float vv[4];
#pragma unroll
        for (int k = 0; k < 4; ++k) vv[k] = T[(lr0 + k) * 132 + cc];
        const int m = m0 + (lr0 >> 4) * 64 + mi * 16 + (lr0 & 15);
        const int bb = m >> 10, l = m & 1023;
        const int pl = (l & ~31) | perm32(l & 31);   // permute l within 32
        uint2 hi; hi.x = pack2hi(vv[0], vv[1]); hi.y = pack2hi(vv[2], vv[3]);
        uint2 lo; lo.x = pack2hi(bfres(vv[0]), bfres(vv[1]));
        lo.y = pack2hi(bfres(vv[2]), bfres(vv[3]));
        const size_t ad = ((size_t)(bb * 16 + h0 + hl) << 16) + (size_t)hd * 1024 + pl;
        *(uint2*)&Vthi[ad] = hi;
        *(uint2*)&Vtlo[ad] = lo;
      }
    }
  }
}

// ---------------------------------------------------------------------------
// Kernel 4: fused attention v8 = attn7 with counted-vmcnt bar2 (T4):
// V staged FIRST (needed this iter), then K/E for rt+1; bar2 waits
// vmcnt(5) (drains only V) so K/E prefetch stays in flight across
// softmax+PV until next bar1's full drain.
// ---------------------------------------------------------------------------
#define KD_OFF 0
#define VD_OFF 32768
#define ER_OFF 49152
#define UB_OFF 81920
#define WB_OFF 115712
#define SM4_SIZE 149504

__global__ __launch_bounds__(512, 2) void attn8_kernel(
    const u16* __restrict__ Qhi, const u16* __restrict__ Qlo,
    const u16* __restrict__ Khi, const u16* __restrict__ Klo,
    const u16* __restrict__ Vthi, const u16* __restrict__ Vtlo,
    const u16* __restrict__ embh, const float* __restrict__ mask,
    float* __restrict__ out) {
  __shared__ __align__(16) char sm[SM4_SIZE];
  char* ERb = sm + ER_OFF;

  const int tid  = threadIdx.x;
  const int lane = tid & 63;
  const int wv   = tid >> 6;
  const int t    = wv >> 2;
  const int lh   = (wv >> 1) & 1;
  const int rh   = wv & 1;
  const int l15  = lane & 15;
  const int g    = lane >> 4;
  const int rsub = lane >> 3;
  const int scol = ((lane & 7) ^ (lane >> 3)) << 3;  // u16 units

  const int bid = (blockIdx.x & 7) * 64 + (blockIdx.x >> 3);  // XCD swizzle
  const int lp = bid & 7, h = (bid >> 3) & 15, b = bid >> 7;
  const int l0 = lp * 128;
  const size_t bhoff = (size_t)(b * 16 + h) << 16;
  const float* maskp = mask + b * L_;

  u16* UBt = (u16*)(sm + UB_OFF) + t * 8448;  // [64][132]
  u16* WBt = (u16*)(sm + WB_OFF) + t * 8448;

  // ---- prologue: stage Q (both planes) into ER area, read this wave's frags
#pragma unroll
  for (int s = 0; s < 4; ++s) {
    const int idx = wv * 4 + s;
    const int plane = idx >> 4, rowg = idx & 15;
    const u16* src = (plane ? Qlo : Qhi) + bhoff +
                     (size_t)(l0 + rowg * 8 + rsub) * 64 + scol;
    gload16(src, ERb + (plane * 16 + rowg) * 1024);
  }
  __syncthreads();

  short8_t qfh[2][2], qfl[2][2];   // [nb][kc]
#pragma unroll
  for (int nb = 0; nb < 2; ++nb)
#pragma unroll
    for (int kc = 0; kc < 2; ++kc) {
      const int row = 64 * t + 32 * lh + 16 * nb + l15;
      qfh[nb][kc] = ldsfragP(ERb,         row, 4 * kc + g);
      qfl[nb][kc] = ldsfragP(ERb + 16384, row, 4 * kc + g);
    }
  __syncthreads();  // ER area free for the E ring

  // ---- per-wave staging source pointers (incremented each iter) ----
  const int pl0 = (wv * 2 + 0) >> 3, rg0 = (wv * 2 + 0) & 7;
  const int pl1 = (wv * 2 + 1) >> 3, rg1 = (wv * 2 + 1) & 7;
  const u16* kb0 = (pl0 ? Klo : Khi) + bhoff + (size_t)(rg0 * 8 + rsub) * 64 + scol;
  const u16* kb1 = (pl1 ? Klo : Khi) + bhoff + (size_t)(rg1 * 8 + rsub) * 64 + scol;
  const u16* vp0 = (pl0 ? Vtlo : Vthi) + bhoff + (size_t)(rg0 * 8 + rsub) * 1024 + scol;
  const u16* vp1 = (pl1 ? Vtlo : Vthi) + bhoff + (size_t)(rg1 * 8 + rsub) * 1024 + scol;
  const u16* ep  = embh + (size_t)(l0 + 896 + wv * 8 + rsub) * 64 + scol;
  const u16* kp0 = kb0 + 4096;
  const u16* kp1 = kb1 + 4096;
  char* const kdst0 = sm + KD_OFF + pl0 * 8192 + rg0 * 1024;
  char* const kdst1 = sm + KD_OFF + pl1 * 8192 + rg1 * 1024;
  char* const vdst0 = sm + VD_OFF + pl0 * 8192 + rg0 * 1024;
  char* const vdst1 = sm + VD_OFF + pl1 * 8192 + rg1 * 1024;

  // ---- initial staging: K[0] (dbuf slot 0) + E window [dmin0, dmin0+191]
  {
    gload16(kb0, kdst0);
    gload16(kb1, kdst1);
    const int dmin0 = l0 + 960;
#pragma unroll
    for (int s = 0; s < 3; ++s) {
      const int grp = wv * 3 + s;  // 0..23
      const int slot = (dmin0 + grp * 8) & 255;
      gload16(embh + (size_t)(dmin0 + grp * 8 + rsub) * 64 + scol,
              ERb + slot * 128);
    }
  }

  f4 o_acc[4][2];
#pragma unroll
  for (int i = 0; i < 4; ++i)
#pragma unroll
    for (int j = 0; j < 2; ++j) o_acc[i][j] = f4{0.f, 0.f, 0.f, 0.f};
  float mrun[2] = {-3e38f, -3e38f};
  float lsum[2] = {0.f, 0.f};

#pragma unroll 2
  for (int rt = 0; rt < 16; ++rt) {
    const int r0 = rt * 64;
    const int cur = rt & 1;
    const int dmin = l0 - r0 + 960;

    __syncthreads();  // (bar1) full drain: K/E prefetch + prev-iter reads done

    // ---- V FIRST (consumed this iter at PV) ----
    gload16(vp0, vdst0);
    gload16(vp1, vdst1);
    vp0 += 64; vp1 += 64;
    __builtin_amdgcn_sched_barrier(0);   // pin: V before K/E in issue order

    // ---- then K[rt+1] + E(rt+1) (drained at NEXT bar1) ----
    if (rt < 15) {
      char* kdn = sm + KD_OFF + (cur ^ 1) * 16384;
      gload16(kp0, kdn + pl0 * 8192 + rg0 * 1024);
      gload16(kp1, kdn + pl1 * 8192 + rg1 * 1024);
      kp0 += 4096; kp1 += 4096;
      const int slot = (dmin - 64 + wv * 8) & 255;
      gload16(ep, ERb + slot * 128);
      ep -= 4096;
    }
    __builtin_amdgcn_sched_barrier(0);   // pin: K/E before mask loads

    // mask prefetch
    float4 mk[2];
#pragma unroll
    for (int mb = 0; mb < 2; ++mb)
      mk[mb] = *(const float4*)&maskp[r0 + 32 * rh + 16 * mb + 4 * g];

    const char* kdc_h = sm + KD_OFF + cur * 16384;
    const char* kdc_l = kdc_h + 8192;

    // ---- QK: S^T = K * Q^T (bf16x3); keep hi K frags for the W GEMM ----
    f4 sacc[2][2];
#pragma unroll
    for (int i = 0; i < 2; ++i)
#pragma unroll
      for (int j = 0; j < 2; ++j) sacc[i][j] = f4{0.f, 0.f, 0.f, 0.f};
    short8_t khf[2][2];
    __builtin_amdgcn_s_setprio(1);
#pragma unroll
    for (int mb = 0; mb < 2; ++mb)
#pragma unroll
      for (int kc = 0; kc < 2; ++kc) {
        const int row = 32 * rh + 16 * mb + l15;
        short8_t ka = ldsfragP(kdc_h, row, 4 * kc + g);
        short8_t kl = ldsfragP(kdc_l, row, 4 * kc + g);
        khf[mb][kc] = ka;
#pragma unroll
        for (int nb = 0; nb < 2; ++nb) {
          sacc[mb][nb] = MF(ka, qfh[nb][kc], sacc[mb][nb]);
          sacc[mb][nb] = MF(ka, qfl[nb][kc], sacc[mb][nb]);
          sacc[mb][nb] = MF(kl, qfh[nb][kc], sacc[mb][nb]);
        }
      }
    __builtin_amdgcn_s_setprio(0);

    // ---- U band GEMM: U^T = E * Q^T -> Ub[l][d] (banded, 6 blocks/pair) ----
#pragma unroll
    for (int s = 0; s < 3; ++s) {
      const int dblk = 16 * (2 * lh + 3 * rh + s);
      const int erow = (dmin + 64 * t + dblk + l15) & 255;
      const short8_t eb0 = ldsfragP(ERb, erow, g);
      const short8_t eb1 = ldsfragP(ERb, erow, 4 + g);
      f4 au0 = f4{0.f, 0.f, 0.f, 0.f}, au1 = f4{0.f, 0.f, 0.f, 0.f};
      au0 = MF(eb0, qfh[0][0], au0); au0 = MF(eb1, qfh[0][1], au0);
      au1 = MF(eb0, qfh[1][0], au1); au1 = MF(eb1, qfh[1][1], au1);
#pragma unroll
      for (int nb = 0; nb < 2; ++nb) {
        const f4 au = nb ? au1 : au0;
        uint2 w2; w2.x = pack2hi(au[0], au[1]); w2.y = pack2hi(au[2], au[3]);
        *(uint2*)&UBt[(32 * lh + 16 * nb + l15) * 132 + dblk + 4 * g] = w2;
      }
    }

    // ---- W band GEMM: W^T = E * K^T -> Wb[r][d] (banded, 6 blocks/pair) ----
#pragma unroll
    for (int s = 0; s < 3; ++s) {
      const int dblk = 16 * ((2 - 2 * rh) + 3 * lh + s);
      const int erow = (dmin + 64 * t + dblk + l15) & 255;
      const short8_t eb0 = ldsfragP(ERb, erow, g);
      const short8_t eb1 = ldsfragP(ERb, erow, 4 + g);
      f4 aw0 = f4{0.f, 0.f, 0.f, 0.f}, aw1 = f4{0.f, 0.f, 0.f, 0.f};
      aw0 = MF(eb0, khf[0][0], aw0); aw0 = MF(eb1, khf[0][1], aw0);
      aw1 = MF(eb0, khf[1][0], aw1); aw1 = MF(eb1, khf[1][1], aw1);
#pragma unroll
      for (int mb = 0; mb < 2; ++mb) {
        const f4 aw = mb ? aw1 : aw0;
        uint2 w2; w2.x = pack2hi(aw[0], aw[1]); w2.y = pack2hi(aw[2], aw[3]);
        *(uint2*)&WBt[(32 * rh + 16 * mb + l15) * 132 + dblk + 4 * g] = w2;
      }
    }

    // ---- bar2 (counted): drain V only (oldest 2); K/E stay in flight ----
    if (rt < 15)
      asm volatile("s_waitcnt vmcnt(5) lgkmcnt(0)\n\ts_barrier" ::: "memory");
    else
      asm volatile("s_waitcnt vmcnt(2) lgkmcnt(0)\n\ts_barrier" ::: "memory");
    __builtin_amdgcn_sched_barrier(0);

    // ---- assembly + online softmax (per-wave rh chain, defer-max) ----
    float pbuf[2][2][4];
#pragma unroll
    for (int nb = 0; nb < 2; ++nb) {
      const int lA = 32 * lh + 16 * nb + l15;
      float sv[2][4];
      float ml = -3e38f;
#pragma unroll
      for (int mb = 0; mb < 2; ++mb) {
        const int rr = 32 * rh + 16 * mb + 4 * g;
        const int dbase = lA + 63 - rr;
        const float mka[4] = {mk[mb].x, mk[mb].y, mk[mb].z, mk[mb].w};
#pragma unroll
        for (int j = 0; j < 4; ++j) {
          const float uu = bf2f(UBt[lA * 132 + dbase - j]);
          const float ww = bf2f(WBt[(rr + j) * 132 + dbase - j]);
          float s = (sacc[mb][nb][j] + uu + ww) * 0.125f + mka[j];
          sv[mb][j] = s;
          ml = fmaxf(ml, s);
        }
      }
      ml = fmaxf(ml, __shfl_xor(ml, 16));
      ml = fmaxf(ml, __shfl_xor(ml, 32));
      const bool nore = __all(ml <= mrun[nb]);     // THR=0: bit-identical path
      const float mn = nore ? mrun[nb] : fmaxf(mrun[nb], ml);
      float ps = 0.f;
#pragma unroll
      for (int mb = 0; mb < 2; ++mb)
#pragma unroll
        for (int j = 0; j < 4; ++j) {
          const float pv = __expf(sv[mb][j] - mn);
          pbuf[nb][mb][j] = pv;
          ps += pv;
        }
      ps += __shfl_xor(ps, 16);
      ps += __shfl_xor(ps, 32);
      if (nore) {
        lsum[nb] += ps;
      } else {
        const float rs = __expf(mrun[nb] - mn);
        lsum[nb] = lsum[nb] * rs + ps;
        mrun[nb] = mn;
#pragma unroll
        for (int mbd = 0; mbd < 4; ++mbd) {
          o_acc[mbd][nb][0] *= rs; o_acc[mbd][nb][1] *= rs;
          o_acc[mbd][nb][2] *= rs; o_acc[mbd][nb][3] *= rs;
        }
      }
    }

    // ---- P fragments (hi/lo) from registers; PV ----
    short8_t pf[2], pl_[2];
#pragma unroll
    for (int nb = 0; nb < 2; ++nb) {
      union { unsigned u[4]; short8_t v; } uh, ul;
      uh.u[0] = pack2hi(pbuf[nb][0][0], pbuf[nb][0][1]);
      uh.u[1] = pack2hi(pbuf[nb][0][2], pbuf[nb][0][3]);
      uh.u[2] = pack2hi(pbuf[nb][1][0], pbuf[nb][1][1]);
      uh.u[3] = pack2hi(pbuf[nb][1][2], pbuf[nb][1][3]);
      pf[nb] = uh.v;
      ul.u[0] = pack2hi(bfres(pbuf[nb][0][0]), bfres(pbuf[nb][0][1]));
      ul.u[1] = pack2hi(bfres(pbuf[nb][0][2]), bfres(pbuf[nb][0][3]));
      ul.u[2] = pack2hi(bfres(pbuf[nb][1][0]), bfres(pbuf[nb][1][1]));
      ul.u[3] = pack2hi(bfres(pbuf[nb][1][2]), bfres(pbuf[nb][1][3]));
      pl_[nb] = ul.v;
    }
    const char* vdc_h = sm + VD_OFF;
    const char* vdc_l = vdc_h + 8192;
    __builtin_amdgcn_s_setprio(1);
#pragma unroll
    for (int mbd = 0; mbd < 4; ++mbd) {
      short8_t vh = ldsfragP(vdc_h, 16 * mbd + l15, 4 * rh + g);
      short8_t vl = ldsfragP(vdc_l, 16 * mbd + l15, 4 * rh + g);
#pragma unroll
      for (int nb = 0; nb < 2; ++nb) {
        o_acc[mbd][nb] = MF(vh, pf[nb], o_acc[mbd][nb]);
        o_acc[mbd][nb] = MF(vh, pl_[nb], o_acc[mbd][nb]);
        o_acc[mbd][nb] = MF(vl, pf[nb], o_acc[mbd][nb]);
      }
    }
    __builtin_amdgcn_s_setprio(0);
  }

  // ---- epilogue: merge the two rh chains (partner wave wv^1), store ----
  __syncthreads();
  float* mbuf = (float*)ERb;
  float* obuf = (float*)(sm + UB_OFF);   // [256][32] f32 = 32 KB
  if (g == 0) {
#pragma unroll
    for (int nb = 0; nb < 2; ++nb) {
      mbuf[((wv * 2 + nb) * 16 + l15) * 2 + 0] = mrun[nb];
      mbuf[((wv * 2 + nb) * 16 + l15) * 2 + 1] = lsum[nb];
    }
  }
  __syncthreads();
  const int pw = wv ^ 1;
  float alpha[2], ltot[2];
#pragma unroll
  for (int nb = 0; nb < 2; ++nb) {
    float m2 = mbuf[((pw * 2 + nb) * 16 + l15) * 2 + 0];
    float s2 = mbuf[((pw * 2 + nb) * 16 + l15) * 2 + 1];
    float M = fmaxf(mrun[nb], m2);
    alpha[nb] = __expf(mrun[nb] - M);
    ltot[nb] = lsum[nb] * alpha[nb] + s2 * __expf(m2 - M);
  }
  const int pair = wv >> 1;   // (t, lh)
  if (rh == 1) {
#pragma unroll
    for (int mbd = 0; mbd < 4; ++mbd)
#pragma unroll
      for (int nb = 0; nb < 2; ++nb)
#pragma unroll
        for (int j = 0; j < 4; ++j)
          obuf[(pair * 64 + 16 * mbd + 4 * g + j) * 32 + 16 * nb + l15] =
              o_acc[mbd][nb][j] * alpha[nb];
  }
  __syncthreads();
  if (rh == 0) {
#pragma unroll
    for (int mbd = 0; mbd < 4; ++mbd)
#pragma unroll
      for (int nb = 0; nb < 2; ++nb) {
        const int lgl = l0 + 64 * t + 32 * lh + 16 * nb + l15;
        const float inv = 1.f / ltot[nb];
        float tmp[4];
#pragma unroll
        for (int j = 0; j < 4; ++j)
          tmp[j] = (o_acc[mbd][nb][j] * alpha[nb] +
                    obuf[(pair * 64 + 16 * mbd + 4 * g + j) * 32 + 16 * nb + l15]) * inv;
        float4 ov; ov.x = tmp[0]; ov.y = tmp[1]; ov.z = tmp[2]; ov.w = tmp[3];
        *(float4*)&out[(size_t)(b * L_ + lgl) * D_ + h * HD_ + 16 * mbd + 4 * g] = ov;
      }
  }
}

// ---------------------------------------------------------------------------
extern "C" void kernel_launch(void* const* d_in, const int* in_sizes, int n_in,
                              void* d_out, int out_size, void* d_ws, size_t ws_size,
                              hipStream_t stream) {
  const float* hs   = (const float*)d_in[0];
  const float* mask = (const float*)d_in[1];
  const float* tw   = (const float*)d_in[2];
  const float* wlw  = (const float*)d_in[3];
  const float* scw  = (const float*)d_in[4];
  const float* shw  = (const float*)d_in[5];
  const float* tb   = (const float*)d_in[6];
  const float* wlb  = (const float*)d_in[7];
  const float* scb  = (const float*)d_in[8];
  const float* shb  = (const float*)d_in[9];
  const float* emb  = (const float*)d_in[10];
  float* out = (float*)d_out;

  char* W = (char*)d_ws;
  float* b_s = (float*)W;                         // 3072 f32
  u16* whi  = (u16*)(W + 12288);
  u16* wlo  = whi + 3145728;
  u16* embh = wlo + 3145728;                      // 2048 rows x 64
  u16* Qhi  = embh + 131072;
  u16* Qlo  = Qhi + 4194304;
  u16* Khi  = Qlo + 4194304;
  u16* Klo  = Khi + 4194304;
  u16* Vthi = Klo + 4194304;
  u16* Vtlo = Vthi + 4194304;
  u16* hhi  = Vtlo + 4194304;                     // hs planes: 4M u16 each
  u16* hlo  = hhi + 4194304;                      // total ~80 MB

  hipLaunchKernelGGL(prep_kernel, dim3(7308), dim3(256), 0, stream,
                     tw, wlw, scw, shw, hs, tb, wlb, scb, shb, emb,
                     whi, wlo, hhi, hlo, embh, b_s);
  hipLaunchKernelGGL(proj_mfma_kernel, dim3(768), dim3(256), 0, stream,
                     hhi, hlo, whi, wlo, b_s, Qhi, Qlo, Khi, Klo, Vthi, Vtlo);
  hipLaunchKernelGGL(attn8_kernel, dim3(512), dim3(512), 0, stream,
                     Qhi, Qlo, Khi, Klo, Vthi, Vtlo, embh, mask, out);
}

// Round 15
// 230.272 us; speedup vs baseline: 1.0051x; 1.0051x over previous
//
#include <hip/hip_runtime.h>
#include <hip/hip_bf16.h>
#include <math.h>

#define D_  1024
#define L_  1024
#define B_  4
#define H_  16
#define HD_ 64

typedef __attribute__((ext_vector_type(4))) short short4_t;
typedef __attribute__((ext_vector_type(8))) short short8_t;
typedef __attribute__((ext_vector_type(4))) float f4;
typedef unsigned short u16;

__device__ __forceinline__ f4 MF(short8_t a, short8_t b, f4 c) {
  return __builtin_amdgcn_mfma_f32_16x16x32_bf16(a, b, c, 0, 0, 0);
}
__device__ __forceinline__ unsigned fbits(float x) { return __builtin_bit_cast(unsigned, x); }
__device__ __forceinline__ float bf2f(unsigned short u) {
  return __builtin_bit_cast(float, (unsigned)u << 16);
}
__device__ __forceinline__ unsigned pack2hi(float x, float y) {
  return (fbits(x) >> 16) | (fbits(y) & 0xFFFF0000u);
}
__device__ __forceinline__ float bfres(float x) {  // x - trunc_bf16(x)
  return x - __builtin_bit_cast(float, fbits(x) & 0xFFFF0000u);
}
__device__ __forceinline__ float ftanh(float x) {  // |x| small here; err < 2e-6
  float t = __expf(2.f * x);
  return (t - 1.f) / (t + 1.f);
}
__device__ __forceinline__ float exp2a(float x) {  // bare v_exp_f32 (2^x)
  float r;
  asm("v_exp_f32 %0, %1" : "=v"(r) : "v"(x));
  return r;
}
__device__ __forceinline__ void gload16(const void* g, void* l) {
  __builtin_amdgcn_global_load_lds(
      (const __attribute__((address_space(1))) unsigned*)g,
      (__attribute__((address_space(3))) unsigned*)l, 16, 0, 0);
}
// ONE ds_read_b128 per MFMA fragment (attn): planes store the k-axis
// pre-permuted within 32-blocks, staging XORs 16B chunks (scol), so chunk
// ci=(kc*4+g)^(row&7) holds the full fragment.
__device__ __forceinline__ short8_t ldsfragP(const char* base, int row, int ci) {
  return *(const short8_t*)(base + row * 128 + ((ci ^ (row & 7)) << 4));
}
// permute a 4-aligned column index within its 32-block
__device__ __forceinline__ int perm32(int c) {
  return (c & ~31) | (((c >> 2) & 3) << 3) | (((c >> 4) & 1) << 2);
}

// ---------------------------------------------------------------------------
// Kernel 1 (fused prep): wgen (blocks 0..3071), hscvt (3072..7167),
// ecvt (7168..7295), bgen (7296..7307).
// ---------------------------------------------------------------------------
__global__ __launch_bounds__(256) void prep_kernel(
    const float* __restrict__ tw, const float* __restrict__ wlw,
    const float* __restrict__ scw, const float* __restrict__ shw,
    const float* __restrict__ hs,
    const float* __restrict__ tb, const float* __restrict__ wlb,
    const float* __restrict__ scb, const float* __restrict__ shb,
    const float* __restrict__ emb,
    u16* __restrict__ whi, u16* __restrict__ wlo,
    u16* __restrict__ hhi, u16* __restrict__ hlo,
    u16* __restrict__ embh, float* __restrict__ b_s) {
  const int blk = blockIdx.x;
  const int tid = threadIdx.x;
  if (blk < 3072) {
    // ---- wgen ----
    size_t i4 = (size_t)blk * 256 + tid;
    size_t e = i4 * 4;
    int p = (int)(e >> 20);
    size_t rem = e & 0xFFFFFu;
    float a0 = wlw[p * 2 + 0], a1 = wlw[p * 2 + 1];
    float4 t0 = *(const float4*)&tw[((size_t)(p * 2 + 0) << 20) + rem];
    float4 t1 = *(const float4*)&tw[((size_t)(p * 2 + 1) << 20) + rem];
    float4 s4 = *(const float4*)&scw[e];
    float4 h4 = *(const float4*)&shw[e];
    float4 o;
    o.x = ftanh(a0 * t0.x + a1 * t1.x) * s4.x + h4.x;
    o.y = ftanh(a0 * t0.y + a1 * t1.y) * s4.y + h4.y;
    o.z = ftanh(a0 * t0.z + a1 * t1.z) * s4.z + h4.z;
    o.w = ftanh(a0 * t0.w + a1 * t1.w) * s4.w + h4.w;
    const size_t off = (e & ~(size_t)31) + perm32((int)(e & 31));
    uint2 hi; hi.x = pack2hi(o.x, o.y); hi.y = pack2hi(o.z, o.w);
    *(uint2*)&whi[off] = hi;
    uint2 lo; lo.x = pack2hi(bfres(o.x), bfres(o.y)); lo.y = pack2hi(bfres(o.z), bfres(o.w));
    *(uint2*)&wlo[off] = lo;
  } else if (blk < 7168) {
    // ---- hscvt ----
    size_t i4 = (size_t)(blk - 3072) * 256 + tid;
    size_t e = i4 * 4;
    float4 v = *(const float4*)&hs[e];
    const size_t off = (e & ~(size_t)31) + perm32((int)(e & 31));
    uint2 hi; hi.x = pack2hi(v.x, v.y); hi.y = pack2hi(v.z, v.w);
    *(uint2*)&hhi[off] = hi;
    uint2 lo; lo.x = pack2hi(bfres(v.x), bfres(v.y)); lo.y = pack2hi(bfres(v.z), bfres(v.w));
    *(uint2*)&hlo[off] = lo;
  } else if (blk < 7296) {
    // ---- ecvt ----
    int i4 = (blk - 7168) * 256 + tid;
    if (i4 >= 32752) return;   // 2047*64/4
    int e = i4 * 4;
    float4 v = *(const float4*)&emb[e];
    uint2 h2; h2.x = pack2hi(v.x, v.y); h2.y = pack2hi(v.z, v.w);
    int pe = (e & ~31) | perm32(e & 31);
    *(uint2*)&embh[pe] = h2;
  } else {
    // ---- bgen ----
    int i = (blk - 7296) * 256 + tid;   // 0..3071
    int p = i >> 10;
    int o = i & 1023;
    float v = ftanh(wlb[p * 2 + 0] * tb[(p * 2 + 0) * D_ + o] +
                    wlb[p * 2 + 1] * tb[(p * 2 + 1) * D_ + o]);
    b_s[i] = v * scb[i] + shb[i];
  }
}

// ---------------------------------------------------------------------------
// Kernel 3: QKV projection, bf16x3 MFMA, double-buffered staging with a
// single barrier per K-tile. LDS dest wave-uniform (rule m104). Slot map:
// A -> SB[.][0/1], B -> SB[.][2/3].  64 KB LDS -> 2 blocks/CU.
// ---------------------------------------------------------------------------
__global__ __launch_bounds__(256, 2) void proj_mfma_kernel(
    const u16* __restrict__ Ahp, const u16* __restrict__ Alp,
    const u16* __restrict__ Bhp, const u16* __restrict__ Blp,
    const float* __restrict__ bias,
    u16* __restrict__ Qhi, u16* __restrict__ Qlo,
    u16* __restrict__ Khi, u16* __restrict__ Klo,
    u16* __restrict__ Vthi, u16* __restrict__ Vtlo) {
  __shared__ u16 SB[2][4][128][32];   // [buf][Ah,Al,Bh,Bl][row][col] = 64 KB
  const int tid  = threadIdx.x;
  const int lane = tid & 63;
  const int wv   = tid >> 6;
  const int wm   = wv >> 1, wn = wv & 1;
  const int l15  = lane & 15, g = lane >> 4;

  const int bid = (blockIdx.x & 7) * 96 + (blockIdx.x >> 3);  // XCD swizzle
  const int mt = bid & 31, nt = bid >> 5;
  const int m0 = mt * 128, n0 = nt * 128;

  f4 acc[4][4];
#pragma unroll
  for (int i = 0; i < 4; ++i)
#pragma unroll
    for (int j = 0; j < 4; ++j) acc[i][j] = f4{0.f, 0.f, 0.f, 0.f};

  const int srow = lane >> 2;            // 0..15 within a 16-row group
  const int sck  = (lane & 3) * 8;       // u16 offset 0,8,16,24

  // ---- per-wave staging descriptors (8 gload16/thread per K-tile) ----
  const u16* sbase[8];
  u16* sdst[8];
#pragma unroll
  for (int s = 0; s < 8; ++s) {
    const int q = wv * 8 + s;          // 0..31
    const int mat   = q >> 4;          // 0 = B, 1 = A
    const int plane = (q >> 3) & 1;    // 0 = hi, 1 = lo
    const int rowg  = q & 7;
    const u16* base = mat ? (plane ? Alp : Ahp) : (plane ? Blp : Bhp);
    const int  rb   = mat ? m0 : n0;
    sbase[s] = base + (size_t)(rb + rowg * 16 + srow) * 1024 + sck;
    sdst[s]  = &SB[0][(mat ^ 1) * 2 + plane][rowg * 16][0];   // A->0/1, B->2/3
  }

  // prologue: stage K-tile 0 into buf 0
#pragma unroll
  for (int s = 0; s < 8; ++s) gload16(sbase[s], sdst[s]);

#pragma unroll 2
  for (int kt = 0; kt < 32; ++kt) {
    const int cur = kt & 1;
    __syncthreads();   // drains staging(cur); prev-iter frag reads done

    if (kt < 31) {
      const int k1 = (kt + 1) * 32;
      const int bo = (cur ^ 1) * 16384;   // u16 offset of other buffer
#pragma unroll
      for (int s = 0; s < 8; ++s) gload16(sbase[s] + k1, sdst[s] + bo);
    }

    const u16 (*SBc)[128][32] = SB[cur];
    short8_t ah[4], al[4], bh[4], bl[4];
#pragma unroll
    for (int i = 0; i < 4; ++i) {
      ah[i] = *(const short8_t*)&SBc[0][wm * 64 + i * 16 + l15][g * 8];
      al[i] = *(const short8_t*)&SBc[1][wm * 64 + i * 16 + l15][g * 8];
      bh[i] = *(const short8_t*)&SBc[2][wn * 64 + i * 16 + l15][g * 8];
      bl[i] = *(const short8_t*)&SBc[3][wn * 64 + i * 16 + l15][g * 8];
    }
    __builtin_amdgcn_s_setprio(1);
#pragma unroll
    for (int mi = 0; mi < 4; ++mi)
#pragma unroll
      for (int ni = 0; ni < 4; ++ni) {
        acc[mi][ni] = MF(ah[mi], bh[ni], acc[mi][ni]);
        acc[mi][ni] = MF(ah[mi], bl[ni], acc[mi][ni]);
        acc[mi][ni] = MF(al[mi], bh[ni], acc[mi][ni]);
      }
    __builtin_amdgcn_s_setprio(0);
  }

  // ---- epilogue: per-mi LDS transpose -> coalesced uint2 plane stores ----
  const int p = n0 >> 10;
  const int h0 = (n0 >> 6) & 15;
  const int nbase = n0 + wn * 64;
  float bnv[4];
#pragma unroll
  for (int ni = 0; ni < 4; ++ni) bnv[ni] = bias[nbase + ni * 16 + l15];
  float* T = (float*)&SB[0][0][0][0];   // 32 x 132 f32

#pragma unroll
  for (int mi = 0; mi < 4; ++mi) {
    __syncthreads();
#pragma unroll
    for (int ni = 0; ni < 4; ++ni)
#pragma unroll
      for (int r = 0; r < 4; ++r)
        T[(wm * 16 + 4 * g + r) * 132 + wn * 64 + ni * 16 + l15] =
            acc[mi][ni][r] + bnv[ni];
    __syncthreads();

    if (p < 2) {
      u16* PH = p ? Khi : Qhi;
      u16* PL = p ? Klo : Qlo;
      const int lr = tid >> 3;
      const int m = m0 + (lr >> 4) * 64 + mi * 16 + (lr & 15);
      const int bb = m >> 10, l = m & 1023;
#pragma unroll
      for (int c = 0; c < 4; ++c) {
        const int col = 4 * (tid & 7) + 32 * c;
        const int pc = perm32(col & 63) | (col & 64);
        const int hd = pc & 63, hl = col >> 6;
        float4 v = *(const float4*)&T[lr * 132 + col];
        uint2 hi; hi.x = pack2hi(v.x, v.y); hi.y = pack2hi(v.z, v.w);
        uint2 lo; lo.x = pack2hi(bfres(v.x), bfres(v.y)); lo.y = pack2hi(bfres(v.z), bfres(v.w));
        const size_t ad = ((size_t)(bb * 16 + h0 + hl) << 16) + (size_t)l * 64 + hd;
        *(uint2*)&PH[ad] = hi;
        *(uint2*)&PL[ad] = lo;
      }
    } else {
      const int col = (tid >> 3) & 31;
#pragma unroll
      for (int c = 0; c < 4; ++c) {
        const int cc = col + 32 * c;
        const int hd = cc & 63, hl = cc >> 6;
        const int mq = tid & 7;
        const int lr0 = 4 * mq;
        float vv[4];
#pragma unroll
        for (int k = 0; k < 4; ++k) vv[k] = T[(lr0 + k) * 132 + cc];
        const int m = m0 + (lr0 >> 4) * 64 + mi * 16 + (lr0 & 15);
        const int bb = m >> 10, l = m & 1023;
        const int pl = (l & ~31) | perm32(l & 31);   // permute l within 32
        uint2 hi; hi.x = pack2hi(vv[0], vv[1]); hi.y = pack2hi(vv[2], vv[3]);
        uint2 lo; lo.x = pack2hi(bfres(vv[0]), bfres(vv[1]));
        lo.y = pack2hi(bfres(vv[2]), bfres(vv[3]));
        const size_t ad = ((size_t)(bb * 16 + h0 + hl) << 16) + (size_t)hd * 1024 + pl;
        *(uint2*)&Vthi[ad] = hi;
        *(uint2*)&Vtlo[ad] = lo;
      }
    }
  }
}

// ---------------------------------------------------------------------------
// Kernel 4: fused attention v9 = attn7 (R13, best) with exp2-domain softmax:
// log2(e) folded into the score scale + mask; every exp is a bare
// v_exp_f32. All softmax state (mrun/lsum/alpha) in log2 domain.
// ---------------------------------------------------------------------------
#define KD_OFF 0
#define VD_OFF 32768
#define ER_OFF 49152
#define UB_OFF 81920
#define WB_OFF 115712
#define SM4_SIZE 149504
#define LOG2E 1.4426950408889634f

__global__ __launch_bounds__(512, 2) void attn9_kernel(
    const u16* __restrict__ Qhi, const u16* __restrict__ Qlo,
    const u16* __restrict__ Khi, const u16* __restrict__ Klo,
    const u16* __restrict__ Vthi, const u16* __restrict__ Vtlo,
    const u16* __restrict__ embh, const float* __restrict__ mask,
    float* __restrict__ out) {
  __shared__ __align__(16) char sm[SM4_SIZE];
  char* ERb = sm + ER_OFF;

  const int tid  = threadIdx.x;
  const int lane = tid & 63;
  const int wv   = tid >> 6;
  const int t    = wv >> 2;
  const int lh   = (wv >> 1) & 1;
  const int rh   = wv & 1;
  const int l15  = lane & 15;
  const int g    = lane >> 4;
  const int rsub = lane >> 3;
  const int scol = ((lane & 7) ^ (lane >> 3)) << 3;  // u16 units

  const int bid = (blockIdx.x & 7) * 64 + (blockIdx.x >> 3);  // XCD swizzle
  const int lp = bid & 7, h = (bid >> 3) & 15, b = bid >> 7;
  const int l0 = lp * 128;
  const size_t bhoff = (size_t)(b * 16 + h) << 16;
  const float* maskp = mask + b * L_;

  u16* UBt = (u16*)(sm + UB_OFF) + t * 8448;  // [64][132]
  u16* WBt = (u16*)(sm + WB_OFF) + t * 8448;

  // ---- prologue: stage Q (both planes) into ER area, read this wave's frags
#pragma unroll
  for (int s = 0; s < 4; ++s) {
    const int idx = wv * 4 + s;
    const int plane = idx >> 4, rowg = idx & 15;
    const u16* src = (plane ? Qlo : Qhi) + bhoff +
                     (size_t)(l0 + rowg * 8 + rsub) * 64 + scol;
    gload16(src, ERb + (plane * 16 + rowg) * 1024);
  }
  __syncthreads();

  short8_t qfh[2][2], qfl[2][2];   // [nb][kc]
#pragma unroll
  for (int nb = 0; nb < 2; ++nb)
#pragma unroll
    for (int kc = 0; kc < 2; ++kc) {
      const int row = 64 * t + 32 * lh + 16 * nb + l15;
      qfh[nb][kc] = ldsfragP(ERb,         row, 4 * kc + g);
      qfl[nb][kc] = ldsfragP(ERb + 16384, row, 4 * kc + g);
    }
  __syncthreads();  // ER area free for the E ring

  // ---- per-wave staging source pointers (incremented each iter) ----
  const int pl0 = (wv * 2 + 0) >> 3, rg0 = (wv * 2 + 0) & 7;
  const int pl1 = (wv * 2 + 1) >> 3, rg1 = (wv * 2 + 1) & 7;
  const u16* kb0 = (pl0 ? Klo : Khi) + bhoff + (size_t)(rg0 * 8 + rsub) * 64 + scol;
  const u16* kb1 = (pl1 ? Klo : Khi) + bhoff + (size_t)(rg1 * 8 + rsub) * 64 + scol;
  const u16* vp0 = (pl0 ? Vtlo : Vthi) + bhoff + (size_t)(rg0 * 8 + rsub) * 1024 + scol;
  const u16* vp1 = (pl1 ? Vtlo : Vthi) + bhoff + (size_t)(rg1 * 8 + rsub) * 1024 + scol;
  const u16* ep  = embh + (size_t)(l0 + 896 + wv * 8 + rsub) * 64 + scol;
  const u16* kp0 = kb0 + 4096;
  const u16* kp1 = kb1 + 4096;
  char* const kdst0 = sm + KD_OFF + pl0 * 8192 + rg0 * 1024;
  char* const kdst1 = sm + KD_OFF + pl1 * 8192 + rg1 * 1024;
  char* const vdst0 = sm + VD_OFF + pl0 * 8192 + rg0 * 1024;
  char* const vdst1 = sm + VD_OFF + pl1 * 8192 + rg1 * 1024;

  // ---- initial staging: K[0] (dbuf slot 0) + E window [dmin0, dmin0+191]
  {
    gload16(kb0, kdst0);
    gload16(kb1, kdst1);
    const int dmin0 = l0 + 960;
#pragma unroll
    for (int s = 0; s < 3; ++s) {
      const int grp = wv * 3 + s;  // 0..23
      const int slot = (dmin0 + grp * 8) & 255;
      gload16(embh + (size_t)(dmin0 + grp * 8 + rsub) * 64 + scol,
              ERb + slot * 128);
    }
  }

  f4 o_acc[4][2];
#pragma unroll
  for (int i = 0; i < 4; ++i)
#pragma unroll
    for (int j = 0; j < 2; ++j) o_acc[i][j] = f4{0.f, 0.f, 0.f, 0.f};
  float mrun[2] = {-3e38f, -3e38f};   // log2 domain
  float lsum[2] = {0.f, 0.f};

#pragma unroll 2
  for (int rt = 0; rt < 16; ++rt) {
    const int r0 = rt * 64;
    const int cur = rt & 1;
    const int dmin = l0 - r0 + 960;

    __syncthreads();  // (bar1) staging for cur drained; prev-iter reads done

    // ---- issue async staging: K[rt+1] + E(rt+1) + V[rt] ----
    if (rt < 15) {
      char* kdn = sm + KD_OFF + (cur ^ 1) * 16384;
      gload16(kp0, kdn + pl0 * 8192 + rg0 * 1024);
      gload16(kp1, kdn + pl1 * 8192 + rg1 * 1024);
      kp0 += 4096; kp1 += 4096;
      const int slot = (dmin - 64 + wv * 8) & 255;
      gload16(ep, ERb + slot * 128);
      ep -= 4096;
    }
    gload16(vp0, vdst0);
    gload16(vp1, vdst1);
    vp0 += 64; vp1 += 64;

    // mask prefetch (pre-scaled to log2 domain)
    float4 mk[2];
#pragma unroll
    for (int mb = 0; mb < 2; ++mb) {
      mk[mb] = *(const float4*)&maskp[r0 + 32 * rh + 16 * mb + 4 * g];
      mk[mb].x *= LOG2E; mk[mb].y *= LOG2E;
      mk[mb].z *= LOG2E; mk[mb].w *= LOG2E;
    }

    const char* kdc_h = sm + KD_OFF + cur * 16384;
    const char* kdc_l = kdc_h + 8192;

    // ---- QK: S^T = K * Q^T (bf16x3); keep hi K frags for the W GEMM ----
    f4 sacc[2][2];
#pragma unroll
    for (int i = 0; i < 2; ++i)
#pragma unroll
      for (int j = 0; j < 2; ++j) sacc[i][j] = f4{0.f, 0.f, 0.f, 0.f};
    short8_t khf[2][2];
    __builtin_amdgcn_s_setprio(1);
#pragma unroll
    for (int mb = 0; mb < 2; ++mb)
#pragma unroll
      for (int kc = 0; kc < 2; ++kc) {
        const int row = 32 * rh + 16 * mb + l15;
        short8_t ka = ldsfragP(kdc_h, row, 4 * kc + g);
        short8_t kl = ldsfragP(kdc_l, row, 4 * kc + g);
        khf[mb][kc] = ka;
#pragma unroll
        for (int nb = 0; nb < 2; ++nb) {
          sacc[mb][nb] = MF(ka, qfh[nb][kc], sacc[mb][nb]);
          sacc[mb][nb] = MF(ka, qfl[nb][kc], sacc[mb][nb]);
          sacc[mb][nb] = MF(kl, qfh[nb][kc], sacc[mb][nb]);
        }
      }
    __builtin_amdgcn_s_setprio(0);

    // ---- U band GEMM: U^T = E * Q^T -> Ub[l][d] (banded, 6 blocks/pair) ----
#pragma unroll
    for (int s = 0; s < 3; ++s) {
      const int dblk = 16 * (2 * lh + 3 * rh + s);
      const int erow = (dmin + 64 * t + dblk + l15) & 255;
      const short8_t eb0 = ldsfragP(ERb, erow, g);
      const short8_t eb1 = ldsfragP(ERb, erow, 4 + g);
      f4 au0 = f4{0.f, 0.f, 0.f, 0.f}, au1 = f4{0.f, 0.f, 0.f, 0.f};
      au0 = MF(eb0, qfh[0][0], au0); au0 = MF(eb1, qfh[0][1], au0);
      au1 = MF(eb0, qfh[1][0], au1); au1 = MF(eb1, qfh[1][1], au1);
#pragma unroll
      for (int nb = 0; nb < 2; ++nb) {
        const f4 au = nb ? au1 : au0;
        uint2 w2; w2.x = pack2hi(au[0], au[1]); w2.y = pack2hi(au[2], au[3]);
        *(uint2*)&UBt[(32 * lh + 16 * nb + l15) * 132 + dblk + 4 * g] = w2;
      }
    }

    // ---- W band GEMM: W^T = E * K^T -> Wb[r][d] (banded, 6 blocks/pair) ----
#pragma unroll
    for (int s = 0; s < 3; ++s) {
      const int dblk = 16 * ((2 - 2 * rh) + 3 * lh + s);
      const int erow = (dmin + 64 * t + dblk + l15) & 255;
      const short8_t eb0 = ldsfragP(ERb, erow, g);
      const short8_t eb1 = ldsfragP(ERb, erow, 4 + g);
      f4 aw0 = f4{0.f, 0.f, 0.f, 0.f}, aw1 = f4{0.f, 0.f, 0.f, 0.f};
      aw0 = MF(eb0, khf[0][0], aw0); aw0 = MF(eb1, khf[0][1], aw0);
      aw1 = MF(eb0, khf[1][0], aw1); aw1 = MF(eb1, khf[1][1], aw1);
#pragma unroll
      for (int mb = 0; mb < 2; ++mb) {
        const f4 aw = mb ? aw1 : aw0;
        uint2 w2; w2.x = pack2hi(aw[0], aw[1]); w2.y = pack2hi(aw[2], aw[3]);
        *(uint2*)&WBt[(32 * rh + 16 * mb + l15) * 132 + dblk + 4 * g] = w2;
      }
    }
    __syncthreads();  // (bar2) U/W visible; staging for this iter drained

    // ---- assembly + online softmax in log2 domain (defer-max) ----
    const float SCL = 0.125f * LOG2E;
    float pbuf[2][2][4];
#pragma unroll
    for (int nb = 0; nb < 2; ++nb) {
      const int lA = 32 * lh + 16 * nb + l15;
      float sv[2][4];
      float ml = -3e38f;
#pragma unroll
      for (int mb = 0; mb < 2; ++mb) {
        const int rr = 32 * rh + 16 * mb + 4 * g;
        const int dbase = lA + 63 - rr;
        const float mka[4] = {mk[mb].x, mk[mb].y, mk[mb].z, mk[mb].w};
#pragma unroll
        for (int j = 0; j < 4; ++j) {
          const float uu = bf2f(UBt[lA * 132 + dbase - j]);
          const float ww = bf2f(WBt[(rr + j) * 132 + dbase - j]);
          float s = (sacc[mb][nb][j] + uu + ww) * SCL + mka[j];
          sv[mb][j] = s;
          ml = fmaxf(ml, s);
        }
      }
      ml = fmaxf(ml, __shfl_xor(ml, 16));
      ml = fmaxf(ml, __shfl_xor(ml, 32));
      const bool nore = __all(ml <= mrun[nb]);     // defer-max, exact path
      const float mn = nore ? mrun[nb] : fmaxf(mrun[nb], ml);
      float ps = 0.f;
#pragma unroll
      for (int mb = 0; mb < 2; ++mb)
#pragma unroll
        for (int j = 0; j < 4; ++j) {
          const float pv = exp2a(sv[mb][j] - mn);
          pbuf[nb][mb][j] = pv;
          ps += pv;
        }
      ps += __shfl_xor(ps, 16);
      ps += __shfl_xor(ps, 32);
      if (nore) {
        lsum[nb] += ps;
      } else {
        const float rs = exp2a(mrun[nb] - mn);
        lsum[nb] = lsum[nb] * rs + ps;
        mrun[nb] = mn;
#pragma unroll
        for (int mbd = 0; mbd < 4; ++mbd) {
          o_acc[mbd][nb][0] *= rs; o_acc[mbd][nb][1] *= rs;
          o_acc[mbd][nb][2] *= rs; o_acc[mbd][nb][3] *= rs;
        }
      }
    }

    // ---- P fragments (hi/lo) from registers; PV ----
    short8_t pf[2], pl_[2];
#pragma unroll
    for (int nb = 0; nb < 2; ++nb) {
      union { unsigned u[4]; short8_t v; } uh, ul;
      uh.u[0] = pack2hi(pbuf[nb][0][0], pbuf[nb][0][1]);
      uh.u[1] = pack2hi(pbuf[nb][0][2], pbuf[nb][0][3]);
      uh.u[2] = pack2hi(pbuf[nb][1][0], pbuf[nb][1][1]);
      uh.u[3] = pack2hi(pbuf[nb][1][2], pbuf[nb][1][3]);
      pf[nb] = uh.v;
      ul.u[0] = pack2hi(bfres(pbuf[nb][0][0]), bfres(pbuf[nb][0][1]));
      ul.u[1] = pack2hi(bfres(pbuf[nb][0][2]), bfres(pbuf[nb][0][3]));
      ul.u[2] = pack2hi(bfres(pbuf[nb][1][0]), bfres(pbuf[nb][1][1]));
      ul.u[3] = pack2hi(bfres(pbuf[nb][1][2]), bfres(pbuf[nb][1][3]));
      pl_[nb] = ul.v;
    }
    const char* vdc_h = sm + VD_OFF;
    const char* vdc_l = vdc_h + 8192;
    __builtin_amdgcn_s_setprio(1);
#pragma unroll
    for (int mbd = 0; mbd < 4; ++mbd) {
      short8_t vh = ldsfragP(vdc_h, 16 * mbd + l15, 4 * rh + g);
      short8_t vl = ldsfragP(vdc_l, 16 * mbd + l15, 4 * rh + g);
#pragma unroll
      for (int nb = 0; nb < 2; ++nb) {
        o_acc[mbd][nb] = MF(vh, pf[nb], o_acc[mbd][nb]);
        o_acc[mbd][nb] = MF(vh, pl_[nb], o_acc[mbd][nb]);
        o_acc[mbd][nb] = MF(vl, pf[nb], o_acc[mbd][nb]);
      }
    }
    __builtin_amdgcn_s_setprio(0);
  }

  // ---- epilogue: merge the two rh chains (partner wave wv^1), store ----
  __syncthreads();
  float* mbuf = (float*)ERb;
  float* obuf = (float*)(sm + UB_OFF);   // [256][32] f32 = 32 KB
  if (g == 0) {
#pragma unroll
    for (int nb = 0; nb < 2; ++nb) {
      mbuf[((wv * 2 + nb) * 16 + l15) * 2 + 0] = mrun[nb];
      mbuf[((wv * 2 + nb) * 16 + l15) * 2 + 1] = lsum[nb];
    }
  }
  __syncthreads();
  const int pw = wv ^ 1;
  float alpha[2], ltot[2];
#pragma unroll
  for (int nb = 0; nb < 2; ++nb) {
    float m2 = mbuf[((pw * 2 + nb) * 16 + l15) * 2 + 0];
    float s2 = mbuf[((pw * 2 + nb) * 16 + l15) * 2 + 1];
    float M = fmaxf(mrun[nb], m2);
    alpha[nb] = exp2a(mrun[nb] - M);
    ltot[nb] = lsum[nb] * alpha[nb] + s2 * exp2a(m2 - M);
  }
  const int pair = wv >> 1;   // (t, lh)
  if (rh == 1) {
#pragma unroll
    for (int mbd = 0; mbd < 4; ++mbd)
#pragma unroll
      for (int nb = 0; nb < 2; ++nb)
#pragma unroll
        for (int j = 0; j < 4; ++j)
          obuf[(pair * 64 + 16 * mbd + 4 * g + j) * 32 + 16 * nb + l15] =
              o_acc[mbd][nb][j] * alpha[nb];
  }
  __syncthreads();
  if (rh == 0) {
#pragma unroll
    for (int mbd = 0; mbd < 4; ++mbd)
#pragma unroll
      for (int nb = 0; nb < 2; ++nb) {
        const int lgl = l0 + 64 * t + 32 * lh + 16 * nb + l15;
        const float inv = 1.f / ltot[nb];
        float tmp[4];
#pragma unroll
        for (int j = 0; j < 4; ++j)
          tmp[j] = (o_acc[mbd][nb][j] * alpha[nb] +
                    obuf[(pair * 64 + 16 * mbd + 4 * g + j) * 32 + 16 * nb + l15]) * inv;
        float4 ov; ov.x = tmp[0]; ov.y = tmp[1]; ov.z = tmp[2]; ov.w = tmp[3];
        *(float4*)&out[(size_t)(b * L_ + lgl) * D_ + h * HD_ + 16 * mbd + 4 * g] = ov;
      }
  }
}

// ---------------------------------------------------------------------------
extern "C" void kernel_launch(void* const* d_in, const int* in_sizes, int n_in,
                              void* d_out, int out_size, void* d_ws, size_t ws_size,
                              hipStream_t stream) {
  const float* hs   = (const float*)d_in[0];
  const float* mask = (const float*)d_in[1];
  const float* tw   = (const float*)d_in[2];
  const float* wlw  = (const float*)d_in[3];
  const float* scw  = (const float*)d_in[4];
  const float* shw  = (const float*)d_in[5];
  const float* tb   = (const float*)d_in[6];
  const float* wlb  = (const float*)d_in[7];
  const float* scb  = (const float*)d_in[8];
  const float* shb  = (const float*)d_in[9];
  const float* emb  = (const float*)d_in[10];
  float* out = (float*)d_out;

  char* W = (char*)d_ws;
  float* b_s = (float*)W;                         // 3072 f32
  u16* whi  = (u16*)(W + 12288);
  u16* wlo  = whi + 3145728;
  u16* embh = wlo + 3145728;                      // 2048 rows x 64
  u16* Qhi  = embh + 131072;
  u16* Qlo  = Qhi + 4194304;
  u16* Khi  = Qlo + 4194304;
  u16* Klo  = Khi + 4194304;
  u16* Vthi = Klo + 4194304;
  u16* Vtlo = Vthi + 4194304;
  u16* hhi  = Vtlo + 4194304;                     // hs planes: 4M u16 each
  u16* hlo  = hhi + 4194304;                      // total ~80 MB

  hipLaunchKernelGGL(prep_kernel, dim3(7308), dim3(256), 0, stream,
                     tw, wlw, scw, shw, hs, tb, wlb, scb, shb, emb,
                     whi, wlo, hhi, hlo, embh, b_s);
  hipLaunchKernelGGL(proj_mfma_kernel, dim3(768), dim3(256), 0, stream,
                     hhi, hlo, whi, wlo, b_s, Qhi, Qlo, Khi, Klo, Vthi, Vtlo);
  hipLaunchKernelGGL(attn9_kernel, dim3(512), dim3(512), 0, stream,
                     Qhi, Qlo, Khi, Klo, Vthi, Vtlo, embh, mask, out);
}